// Round 3
// baseline (300.424 us; speedup 1.0000x reference)
//
#include <hip/hip_runtime.h>
#include <stdint.h>
#include <stddef.h>

typedef _Float16 f16;
typedef __attribute__((ext_vector_type(8))) _Float16 f16x8;
typedef __attribute__((ext_vector_type(4))) float f32x4;

#define GPTR(p) ((const __attribute__((address_space(1))) void*)(p))
#define LPTR(p) ((__attribute__((address_space(3))) void*)(p))

// async global->LDS, 16B per lane; LDS dest = wave-uniform base + lane*16
__device__ __forceinline__ void async16(const void* g, void* l) {
    __builtin_amdgcn_global_load_lds(GPTR(g), LPTR(l), 16, 0, 0);
}

// ---------------------------------------------------------------------------
// Sparsify (2:4 soft-threshold along last dim of W[K][M]) * scale -> fp16,
// stored transposed Wt[M][K]. Tiled 64x64 with LDS transpose.
// ---------------------------------------------------------------------------
__global__ __launch_bounds__(256) void sparsify_t_tiled(
        const float* __restrict__ W, const float* __restrict__ scale,
        f16* __restrict__ Wt, int K, int M) {
    __shared__ f16 T[64][80];
    const int r0 = blockIdx.y << 6, m0 = blockIdx.x << 6;
    const float s = scale[0];
    const int t = threadIdx.x;
    const int rr = t >> 2, mb = (t & 3) << 4;
    const float* src = W + (size_t)(r0 + rr) * M + m0 + mb;
    #pragma unroll
    for (int j = 0; j < 4; j++) {
        float4 v = *(const float4*)(src + j * 4);
        float a0 = fabsf(v.x), a1 = fabsf(v.y), a2 = fabsf(v.z), a3 = fabsf(v.w);
        float lo1 = fminf(a0, a1), hi1 = fmaxf(a0, a1);
        float lo2 = fminf(a2, a3), hi2 = fmaxf(a2, a3);
        float th = fminf(fmaxf(lo1, lo2), fminf(hi1, hi2));
        int m = mb + j * 4;
        T[m + 0][rr] = (f16)(copysignf(fmaxf(a0 - th, 0.f), v.x) * s);
        T[m + 1][rr] = (f16)(copysignf(fmaxf(a1 - th, 0.f), v.y) * s);
        T[m + 2][rr] = (f16)(copysignf(fmaxf(a2 - th, 0.f), v.z) * s);
        T[m + 3][rr] = (f16)(copysignf(fmaxf(a3 - th, 0.f), v.w) * s);
    }
    __syncthreads();
    const int mm = t >> 2, rb = (t & 3) << 4;
    f16* dst = Wt + (size_t)(m0 + mm) * K + r0 + rb;
    *(f16x8*)dst       = *(const f16x8*)&T[mm][rb];
    *(f16x8*)(dst + 8) = *(const f16x8*)&T[mm][rb + 8];
}

// ---------------------------------------------------------------------------
// GEMM1: H[16384][256](f16) = fp16(x[16384][2048]) @ W1t[256][2048]^T + b1
// BM=32 BN=64 BK=64. Grid 2048 blocks (8/CU). XCD swizzle: the 4 col-tiles
// of a row-block share an XCD (NC=4), so x is HBM-fetched once per row.
// 4 waves as 2x2; wave tile 16x32 (1x2 of 16x16x32 MFMA).
// LDS XOR-swizzled 16B granules (global_load_lds forbids padding).
// ---------------------------------------------------------------------------
__global__ __launch_bounds__(256, 8) void gemm1_kernel(
        const float* __restrict__ A, const f16* __restrict__ Bt,
        const float* __restrict__ bias, f16* __restrict__ H) {
    constexpr int K = 2048, RN = 256, BK = 64;
    __shared__ float4 Asf[32 * 16];   // 8 KB swizzled [r][p]
    __shared__ f16x8  Bs[64 * 8];     // 8 KB swizzled [r][p]

    const int f = blockIdx.x;
    const int xcd = f & 7, j = f >> 3;
    const int row0 = (xcd + ((j >> 2) << 3)) << 5;   // row-block*32
    const int col0 = (j & 3) << 6;                   // col-tile*64

    const int tid  = threadIdx.x;
    const int lane = tid & 63;
    const int wv   = tid >> 6;
    const int wm   = wv & 1, wn = wv >> 1;
    const int lr   = lane & 15, q = lane >> 4;

    f32x4 acc[2] = {};

    for (int k0 = 0; k0 < K; k0 += BK) {
        #pragma unroll
        for (int jj = 0; jj < 2; jj++) {     // A: 8 issues of 1 KB
            int issue = wv * 2 + jj;
            int L = issue * 64 + lane;
            int r = L >> 4, p = L & 15;
            int c = (p & 8) | ((p & 7) ^ (r & 7));
            async16(A + (size_t)(row0 + r) * K + k0 + c * 4, &Asf[issue * 64]);
        }
        #pragma unroll
        for (int jj = 0; jj < 2; jj++) {     // B: 8 issues of 1 KB
            int issue = wv * 2 + jj;
            int L = issue * 64 + lane;
            int r = L >> 3, p = L & 7;
            int c = p ^ (r & 7);
            async16(Bt + (size_t)(col0 + r) * K + k0 + c * 8, &Bs[issue * 64]);
        }
        __syncthreads();

        #pragma unroll
        for (int ks = 0; ks < 2; ks++) {
            int ar = wm * 16 + lr;
            int c0 = ks * 8 + 2 * q, c1 = c0 + 1;
            float4 v0 = Asf[ar * 16 + ((c0 & 8) | ((c0 & 7) ^ (ar & 7)))];
            float4 v1 = Asf[ar * 16 + ((c1 & 8) | ((c1 & 7) ^ (ar & 7)))];
            f16x8 af;
            af[0] = (f16)v0.x; af[1] = (f16)v0.y; af[2] = (f16)v0.z; af[3] = (f16)v0.w;
            af[4] = (f16)v1.x; af[5] = (f16)v1.y; af[6] = (f16)v1.z; af[7] = (f16)v1.w;
            #pragma unroll
            for (int n = 0; n < 2; n++) {
                int br = wn * 32 + n * 16 + lr;
                f16x8 bf = Bs[br * 8 + ((ks * 4 + q) ^ (br & 7))];
                acc[n] = __builtin_amdgcn_mfma_f32_16x16x32_f16(af, bf, acc[n], 0, 0, 0);
            }
        }
        __syncthreads();
    }

    const int gr0 = row0 + wm * 16 + q * 4;
    #pragma unroll
    for (int n = 0; n < 2; n++) {
        int gc = col0 + wn * 32 + n * 16 + lr;
        float bv = bias[gc];
        #pragma unroll
        for (int r = 0; r < 4; r++)
            H[(size_t)(gr0 + r) * RN + gc] = (f16)(acc[n][r] + bv);
    }
}

// ---------------------------------------------------------------------------
// GEMM2: y[16384][2048](f32) = H[16384][256](f16) @ W2t[2048][256]^T + b2
// BM=64 BN=64 BK=64 (4 K-iters). Grid 8192 blocks (8/CU). XCD swizzle with
// NC=32: a row-block's 32 col-tiles share an XCD -> H re-reads hit L2.
// 4 waves as 2x2; wave tile 32x32.
// ---------------------------------------------------------------------------
__global__ __launch_bounds__(256, 8) void gemm2_kernel(
        const f16* __restrict__ H, const f16* __restrict__ Bt,
        const float* __restrict__ bias, float* __restrict__ Y) {
    constexpr int K = 256, N = 2048, BK = 64;
    __shared__ f16x8 As[64 * 8];    // 8 KB
    __shared__ f16x8 Bs[64 * 8];    // 8 KB

    const int f = blockIdx.x;
    const int xcd = f & 7, j = f >> 3;
    const int row0 = (xcd + ((j >> 5) << 3)) << 6;   // row-block*64
    const int col0 = (j & 31) << 6;                  // col-tile*64

    const int tid  = threadIdx.x;
    const int lane = tid & 63;
    const int wv   = tid >> 6;
    const int wm   = wv & 1, wn = wv >> 1;
    const int lr   = lane & 15, q = lane >> 4;

    f32x4 acc[2][2] = {};

    for (int k0 = 0; k0 < K; k0 += BK) {
        #pragma unroll
        for (int jj = 0; jj < 2; jj++) {
            int issue = wv * 2 + jj;
            int L = issue * 64 + lane;
            int r = L >> 3, p = L & 7;
            int c = p ^ (r & 7);
            async16(H + (size_t)(row0 + r) * K + k0 + c * 8, &As[issue * 64]);
        }
        #pragma unroll
        for (int jj = 0; jj < 2; jj++) {
            int issue = wv * 2 + jj;
            int L = issue * 64 + lane;
            int r = L >> 3, p = L & 7;
            int c = p ^ (r & 7);
            async16(Bt + (size_t)(col0 + r) * K + k0 + c * 8, &Bs[issue * 64]);
        }
        __syncthreads();

        #pragma unroll
        for (int ks = 0; ks < 2; ks++) {
            f16x8 af[2], bf[2];
            #pragma unroll
            for (int m = 0; m < 2; m++) {
                int r = wm * 32 + m * 16 + lr;
                af[m] = As[r * 8 + ((ks * 4 + q) ^ (r & 7))];
            }
            #pragma unroll
            for (int n = 0; n < 2; n++) {
                int r = wn * 32 + n * 16 + lr;
                bf[n] = Bs[r * 8 + ((ks * 4 + q) ^ (r & 7))];
            }
            #pragma unroll
            for (int m = 0; m < 2; m++)
                #pragma unroll
                for (int n = 0; n < 2; n++)
                    acc[m][n] = __builtin_amdgcn_mfma_f32_16x16x32_f16(
                        af[m], bf[n], acc[m][n], 0, 0, 0);
        }
        __syncthreads();
    }

    #pragma unroll
    for (int m = 0; m < 2; m++) {
        int gr0 = row0 + wm * 32 + m * 16 + q * 4;
        #pragma unroll
        for (int n = 0; n < 2; n++) {
            int gc = col0 + wn * 32 + n * 16 + lr;
            float bv = bias[gc];
            #pragma unroll
            for (int r = 0; r < 4; r++)
                Y[(size_t)(gr0 + r) * N + gc] = acc[m][n][r] + bv;
        }
    }
}

// ---------------------------------------------------------------------------
// launch
// ---------------------------------------------------------------------------
extern "C" void kernel_launch(void* const* d_in, const int* in_sizes, int n_in,
                              void* d_out, int out_size, void* d_ws, size_t ws_size,
                              hipStream_t stream) {
    const float* x  = (const float*)d_in[0];
    const float* w1 = (const float*)d_in[1];
    const float* w2 = (const float*)d_in[2];
    const float* b1 = (const float*)d_in[3];
    const float* b2 = (const float*)d_in[4];
    const float* s1 = (const float*)d_in[5];
    const float* s2 = (const float*)d_in[6];
    float* y = (float*)d_out;

    constexpr int NROWS = 8 * 2048;  // 16384
    constexpr int D = 2048, R = 256;

    char* ws = (char*)d_ws;
    f16* W1t = (f16*)ws;                             // [R][D]  fp16, 1 MiB
    f16* W2t = (f16*)(ws + (size_t)R * D * 2);       // [D][R]  fp16, 1 MiB
    f16* H   = (f16*)(ws + (size_t)R * D * 4);       // [NROWS][R] fp16, 8 MiB

    hipLaunchKernelGGL(sparsify_t_tiled, dim3(R / 64, D / 64), dim3(256),
                       0, stream, w1, s1, W1t, D, R);
    hipLaunchKernelGGL(sparsify_t_tiled, dim3(D / 64, R / 64), dim3(256),
                       0, stream, w2, s2, W2t, R, D);

    // GEMM1: 512 row-blocks x 4 col-tiles = 2048 blocks (8/CU)
    hipLaunchKernelGGL(gemm1_kernel, dim3(2048), dim3(256), 0, stream,
                       x, W1t, b1, H);

    // GEMM2: 256 row-blocks x 32 col-tiles = 8192 blocks
    hipLaunchKernelGGL(gemm2_kernel, dim3(8192), dim3(256), 0, stream,
                       H, W2t, b2, y);
}